// Round 1
// baseline (529.615 us; speedup 1.0000x reference)
//
#include <hip/hip_runtime.h>
#include <math.h>

#define B_ 2
#define T_ 512
#define N_ 512
#define H_ 64

// ---------------------------------------------------------------------------
// Kernel 1: dynamic context (mean, std, last-observed, missing ratio) per (b,n)
// grid: B*32 blocks of 256 threads; 16 n-lanes x 16 t-chunks, coalesced over n.
// ---------------------------------------------------------------------------
__global__ void dyn_kernel(const float* __restrict__ x, const float* __restrict__ mask,
                           float* __restrict__ dyn) {
    int blk = blockIdx.x;
    int b  = blk >> 5;
    int n0 = (blk & 31) << 4;
    int tn = threadIdx.x & 15;
    int tt = threadIdx.x >> 4;
    int n  = n0 + tn;

    float sx = 0.f, sxx = 0.f, cnt = 0.f, msum = 0.f, bv = 0.f;
    int bt = -1;
    for (int t = tt; t < T_; t += 16) {
        int off = (b * T_ + t) * N_ + n;
        float xv = x[off];
        float mv = mask[off];
        float obs = 1.f - mv;
        sx   += xv * obs;
        sxx  += xv * xv * obs;
        cnt  += obs;
        msum += mv;
        if (obs > 0.5f) { bt = t; bv = xv; }   // t increasing -> latest observed
    }

    __shared__ float red[5][16][16];
    __shared__ int   redt[16][16];
    red[0][tt][tn] = sx;  red[1][tt][tn] = sxx; red[2][tt][tn] = cnt;
    red[3][tt][tn] = msum; red[4][tt][tn] = bv; redt[tt][tn] = bt;
    __syncthreads();

    if (threadIdx.x < 16) {
        int tn2 = threadIdx.x;
        float Sx = 0.f, Sxx = 0.f, Cnt = 0.f, Ms = 0.f, Bv = 0.f;
        int Bt = -1;
        for (int u = 0; u < 16; u++) {
            Sx  += red[0][u][tn2];
            Sxx += red[1][u][tn2];
            Cnt += red[2][u][tn2];
            Ms  += red[3][u][tn2];
            int btu = redt[u][tn2];
            if (btu > Bt) { Bt = btu; Bv = red[4][u][tn2]; }
        }
        int nn = n0 + tn2;
        float count = fmaxf(Cnt, 1.f);
        float mean  = Sx / count;
        float var   = (Sxx - 2.f * mean * Sx + mean * mean * Cnt) / count;
        float stdv  = sqrtf(fmaxf(var, 0.f) + 1e-6f);
        float last  = (Bt >= 0) ? Bv : x[(b * T_ + 0) * N_ + nn];  // argmax of zeros -> t=0
        float mr    = Ms * (1.f / (float)T_);
        int base = (b * N_ + nn) * 4;
        dyn[base + 0] = mean;
        dyn[base + 1] = stdv;
        dyn[base + 2] = last;
        dyn[base + 3] = mr;
    }
}

// ---------------------------------------------------------------------------
// Kernel 2: per-node MLP (12 -> 64 -> 64) + precompute P = r@W3[0:64],
// Q = r@W3[64:128]. One 64-thread block per (b,n).
// ---------------------------------------------------------------------------
__global__ __launch_bounds__(64) void mlp_kernel(
        const float* __restrict__ dyn, const float* __restrict__ sc,
        const float* __restrict__ W1, const float* __restrict__ b1,
        const float* __restrict__ W2, const float* __restrict__ b2,
        const float* __restrict__ W3,
        float* __restrict__ nr, float* __restrict__ P, float* __restrict__ Q) {
    int blk = blockIdx.x;
    int b = blk >> 9;
    int n = blk & (N_ - 1);
    int o = threadIdx.x;

    __shared__ float f[12];
    __shared__ float h[H_];
    __shared__ float r[H_];

    if (o < 4)        f[o] = dyn[(b * N_ + n) * 4 + o];
    else if (o < 12)  f[o] = sc[n * 8 + (o - 4)];
    __syncthreads();

    float a = b1[o];
#pragma unroll
    for (int k = 0; k < 12; k++) a += f[k] * W1[k * H_ + o];
    h[o] = fmaxf(a, 0.f);
    __syncthreads();

    float a2 = b2[o];
#pragma unroll 8
    for (int k = 0; k < H_; k++) a2 += h[k] * W2[k * H_ + o];
    float rv = fmaxf(a2, 0.f);
    r[o] = rv;
    nr[(b * N_ + n) * H_ + o] = rv;
    __syncthreads();

    float p = 0.f, q = 0.f;
#pragma unroll 8
    for (int k = 0; k < H_; k++) {
        float rk = r[k];
        p += rk * W3[k * H_ + o];
        q += rk * W3[(H_ + k) * H_ + o];
    }
    P[(b * N_ + n) * H_ + o] = p;
    Q[(b * N_ + n) * H_ + o] = q;
}

// ---------------------------------------------------------------------------
// Kernel 3: pairwise edge MLP. One block (256 thr = 4 waves) per (b,i).
// e[o] = relu(b3[o] + P[i][o] + Q[j][o] + sum_k |hi-hj|*W3c[k][o] + (hi*hj)*W3d[k][o])
// edge = relu(e . W4 + b4); adapt = edge*prior(i,j) (+1 on diag); degree = rowsum.
// ---------------------------------------------------------------------------
__global__ __launch_bounds__(256) void pair_kernel(
        const float* __restrict__ nr, const float* __restrict__ P,
        const float* __restrict__ Q,  const float* __restrict__ W3,
        const float* __restrict__ b3, const float* __restrict__ W4,
        const float* __restrict__ b4, const float* __restrict__ coords,
        float* __restrict__ adapt, float* __restrict__ degree) {
    int blk = blockIdx.x;
    int b = blk >> 9;
    int i = blk & (N_ - 1);
    int tid = threadIdx.x;
    int o = tid & 63;
    int w = tid >> 6;

    __shared__ float sWcd[H_ * 128];   // interleaved [k][2o]=W3c[k][o], [2o+1]=W3d[k][o]
    __shared__ float sHi[H_];
    __shared__ float sHj[4][H_];
    __shared__ float sCi[8];
    __shared__ float sRow[4];

    for (int idx = tid; idx < H_ * H_; idx += 256) {
        int k = idx >> 6;
        int oo = idx & 63;
        sWcd[k * 128 + 2 * oo]     = W3[(128 + k) * H_ + oo];
        sWcd[k * 128 + 2 * oo + 1] = W3[(192 + k) * H_ + oo];
    }
    if (tid < H_) sHi[tid] = nr[(b * N_ + i) * H_ + tid];
    if (tid < 8)  sCi[tid] = coords[i * 8 + tid];
    __syncthreads();

    float pr  = b3[o] + P[(b * N_ + i) * H_ + o];
    float w4o = W4[o];
    float b4s = b4[0];
    float rowsum = 0.f;

    for (int j = w; j < N_; j += 4) {
        // stage hj for this wave (wave-private LDS, in-order DS pipe => no barrier)
        sHj[w][o] = nr[(b * N_ + j) * H_ + o];

        float acc = pr + Q[(b * N_ + j) * H_ + o];
#pragma unroll
        for (int k = 0; k < H_; k++) {
            float hik = sHi[k];
            float hjk = sHj[w][k];
            float d = fabsf(hik - hjk);
            float m = hik * hjk;
            float wc = sWcd[k * 128 + 2 * o];
            float wd = sWcd[k * 128 + 2 * o + 1];
            acc += d * wc;
            acc += m * wd;
        }
        float e = fmaxf(acc, 0.f);
        float p = e * w4o;
#pragma unroll
        for (int off = 32; off > 0; off >>= 1) p += __shfl_xor(p, off);
        float edge = fmaxf(p + b4s, 0.f);

        // prior adjacency (wave-uniform scalar loads of coords[j])
        float d2 = 0.f;
#pragma unroll
        for (int c = 0; c < 8; c++) {
            float df = sCi[c] - coords[j * 8 + c];
            d2 += df * df;
        }
        float dist = (d2 > 0.f) ? sqrtf(d2) : 0.f;
        float priorv = 1.f / (1.f + dist);
        float ad = (i == j) ? 1.0f : edge * priorv;   // SELF_LOOP_W = 1, prior diag = 0

        if (o == 0) adapt[(b * N_ + i) * N_ + j] = ad;
        rowsum += ad;
    }

    if (o == 0) sRow[w] = rowsum;
    __syncthreads();
    if (tid == 0) degree[b * N_ + i] = sRow[0] + sRow[1] + sRow[2] + sRow[3];
}

// ---------------------------------------------------------------------------
// Kernel 4: symmetric normalization out = D^-1/2 A D^-1/2
// ---------------------------------------------------------------------------
__global__ void norm_kernel(const float* __restrict__ adapt, const float* __restrict__ deg,
                            float* __restrict__ out) {
    int idx = blockIdx.x * 256 + threadIdx.x;
    int b = idx >> 18;
    int r = (idx >> 9) & (N_ - 1);
    int c = idx & (N_ - 1);
    float dr = rsqrtf(fmaxf(deg[b * N_ + r], 1e-6f));
    float dc = rsqrtf(fmaxf(deg[b * N_ + c], 1e-6f));
    out[idx] = dr * adapt[idx] * dc;
}

extern "C" void kernel_launch(void* const* d_in, const int* in_sizes, int n_in,
                              void* d_out, int out_size, void* d_ws, size_t ws_size,
                              hipStream_t stream) {
    const float* x      = (const float*)d_in[0];
    const float* mask   = (const float*)d_in[1];
    const float* sc     = (const float*)d_in[2];
    const float* coords = (const float*)d_in[3];
    const float* W1 = (const float*)d_in[4];
    const float* b1 = (const float*)d_in[5];
    const float* W2 = (const float*)d_in[6];
    const float* b2 = (const float*)d_in[7];
    const float* W3 = (const float*)d_in[8];
    const float* b3 = (const float*)d_in[9];
    const float* W4 = (const float*)d_in[10];
    const float* b4 = (const float*)d_in[11];
    float* out = (float*)d_out;

    float* w = (float*)d_ws;
    float* dyn   = w;                      // B*N*4      = 4096
    float* nr    = w + 4096;               // B*N*64     = 65536
    float* P     = w + 69632;              // 65536
    float* Q     = w + 135168;             // 65536
    float* adapt = w + 200704;             // B*N*N      = 524288
    float* deg   = w + 724992;             // B*N        = 1024

    dyn_kernel<<<B_ * 32, 256, 0, stream>>>(x, mask, dyn);
    mlp_kernel<<<B_ * N_, 64, 0, stream>>>(dyn, sc, W1, b1, W2, b2, W3, nr, P, Q);
    pair_kernel<<<B_ * N_, 256, 0, stream>>>(nr, P, Q, W3, b3, W4, b4, coords, adapt, deg);
    norm_kernel<<<(B_ * N_ * N_) / 256, 256, 0, stream>>>(adapt, deg, out);
}

// Round 2
// 144.425 us; speedup vs baseline: 3.6671x; 3.6671x over previous
//
#include <hip/hip_runtime.h>
#include <math.h>

#define B_ 2
#define T_ 512
#define N_ 512
#define H_ 64

typedef __attribute__((ext_vector_type(8))) short short8;
typedef __attribute__((ext_vector_type(4))) float floatx4;

__device__ inline short f2bf(float f) {
    union { float f; unsigned u; } v; v.f = f;
    unsigned r = (v.u + 0x7fffu + ((v.u >> 16) & 1u)) >> 16;  // RNE
    return (short)r;
}

// ---------------------------------------------------------------------------
// Kernel 1: dynamic context (mean, std, last-observed, missing ratio) per (b,n)
// ---------------------------------------------------------------------------
__global__ void dyn_kernel(const float* __restrict__ x, const float* __restrict__ mask,
                           float* __restrict__ dyn) {
    int blk = blockIdx.x;
    int b  = blk >> 5;
    int n0 = (blk & 31) << 4;
    int tn = threadIdx.x & 15;
    int tt = threadIdx.x >> 4;
    int n  = n0 + tn;

    float sx = 0.f, sxx = 0.f, cnt = 0.f, msum = 0.f, bv = 0.f;
    int bt = -1;
    for (int t = tt; t < T_; t += 16) {
        int off = (b * T_ + t) * N_ + n;
        float xv = x[off];
        float mv = mask[off];
        float obs = 1.f - mv;
        sx   += xv * obs;
        sxx  += xv * xv * obs;
        cnt  += obs;
        msum += mv;
        if (obs > 0.5f) { bt = t; bv = xv; }
    }

    __shared__ float red[5][16][16];
    __shared__ int   redt[16][16];
    red[0][tt][tn] = sx;  red[1][tt][tn] = sxx; red[2][tt][tn] = cnt;
    red[3][tt][tn] = msum; red[4][tt][tn] = bv; redt[tt][tn] = bt;
    __syncthreads();

    if (threadIdx.x < 16) {
        int tn2 = threadIdx.x;
        float Sx = 0.f, Sxx = 0.f, Cnt = 0.f, Ms = 0.f, Bv = 0.f;
        int Bt = -1;
        for (int u = 0; u < 16; u++) {
            Sx  += red[0][u][tn2];
            Sxx += red[1][u][tn2];
            Cnt += red[2][u][tn2];
            Ms  += red[3][u][tn2];
            int btu = redt[u][tn2];
            if (btu > Bt) { Bt = btu; Bv = red[4][u][tn2]; }
        }
        int nn = n0 + tn2;
        float count = fmaxf(Cnt, 1.f);
        float mean  = Sx / count;
        float var   = (Sxx - 2.f * mean * Sx + mean * mean * Cnt) / count;
        float stdv  = sqrtf(fmaxf(var, 0.f) + 1e-6f);
        float last  = (Bt >= 0) ? Bv : x[(b * T_ + 0) * N_ + nn];
        float mr    = Ms * (1.f / (float)T_);
        int base = (b * N_ + nn) * 4;
        dyn[base + 0] = mean;
        dyn[base + 1] = stdv;
        dyn[base + 2] = last;
        dyn[base + 3] = mr;
    }
}

// ---------------------------------------------------------------------------
// Kernel 2: per-node MLP (12 -> 64 -> 64) + P = r@W3[0:64], Q = r@W3[64:128]
// ---------------------------------------------------------------------------
__global__ __launch_bounds__(64) void mlp_kernel(
        const float* __restrict__ dyn, const float* __restrict__ sc,
        const float* __restrict__ W1, const float* __restrict__ b1,
        const float* __restrict__ W2, const float* __restrict__ b2,
        const float* __restrict__ W3,
        float* __restrict__ nr, float* __restrict__ P, float* __restrict__ Q) {
    int blk = blockIdx.x;
    int b = blk >> 9;
    int n = blk & (N_ - 1);
    int o = threadIdx.x;

    __shared__ float f[12];
    __shared__ float h[H_];
    __shared__ float r[H_];

    if (o < 4)        f[o] = dyn[(b * N_ + n) * 4 + o];
    else if (o < 12)  f[o] = sc[n * 8 + (o - 4)];
    __syncthreads();

    float a = b1[o];
#pragma unroll
    for (int k = 0; k < 12; k++) a += f[k] * W1[k * H_ + o];
    h[o] = fmaxf(a, 0.f);
    __syncthreads();

    float a2 = b2[o];
#pragma unroll 8
    for (int k = 0; k < H_; k++) a2 += h[k] * W2[k * H_ + o];
    float rv = fmaxf(a2, 0.f);
    r[o] = rv;
    nr[(b * N_ + n) * H_ + o] = rv;
    __syncthreads();

    float p = 0.f, q = 0.f;
#pragma unroll 8
    for (int k = 0; k < H_; k++) {
        float rk = r[k];
        p += rk * W3[k * H_ + o];
        q += rk * W3[(H_ + k) * H_ + o];
    }
    P[(b * N_ + n) * H_ + o] = p;
    Q[(b * N_ + n) * H_ + o] = q;
}

// ---------------------------------------------------------------------------
// Kernel 3 (MFMA): per (b,i), C[j,o] = [D|M](512x128) @ W3[128:256](128x64),
// fragments built in registers; epilogue: +P+Q+b3, relu, dot W4, relu, prior.
// 16x16x32 bf16: A lane: m=lane&15, k=quad*8+t; C/D lane: col=lane&15,
// row=quad*4+reg.
// ---------------------------------------------------------------------------
__global__ __launch_bounds__(256) void pair_mfma_kernel(
        const float* __restrict__ nr, const float* __restrict__ P,
        const float* __restrict__ Q,  const float* __restrict__ W3,
        const float* __restrict__ b3, const float* __restrict__ W4,
        const float* __restrict__ b4, const float* __restrict__ coords,
        float* __restrict__ adapt, float* __restrict__ degree) {
    int blk = blockIdx.x;
    int b = blk >> 9;
    int i = blk & (N_ - 1);
    int tid = threadIdx.x;
    int w = tid >> 6;
    int l = tid & 63;
    int col = l & 15;
    int quad = l >> 4;

    // B fragments (per-block constant): bf[s][nt][t] = W3[(128+s*32+quad*8+t)*64 + nt*16+col]
    short8 bf[4][4];
#pragma unroll
    for (int s = 0; s < 4; s++) {
#pragma unroll
        for (int nt = 0; nt < 4; nt++) {
#pragma unroll
            for (int t = 0; t < 8; t++) {
                bf[s][nt][t] = f2bf(W3[(128 + s * 32 + quad * 8 + t) * H_ + nt * 16 + col]);
            }
        }
    }

    // hi chunks this lane needs: k = quad*8..+7 and 32+quad*8..+7
    const float* hi_row = nr + (b * N_ + i) * H_;
    floatx4 hiA0 = *(const floatx4*)(hi_row + quad * 8);
    floatx4 hiA1 = *(const floatx4*)(hi_row + quad * 8 + 4);
    floatx4 hiB0 = *(const floatx4*)(hi_row + 32 + quad * 8);
    floatx4 hiB1 = *(const floatx4*)(hi_row + 32 + quad * 8 + 4);

    float pb3[4], w4v[4];
#pragma unroll
    for (int nt = 0; nt < 4; nt++) {
        int o = nt * 16 + col;
        pb3[nt] = P[(b * N_ + i) * H_ + o] + b3[o];
        w4v[nt] = W4[o];
    }
    float b4s = b4[0];

    float ci[8];
#pragma unroll
    for (int c = 0; c < 8; c++) ci[c] = coords[i * 8 + c];

    float rsum = 0.f;

    for (int mt = 0; mt < 8; mt++) {
        int j0 = w * 128 + mt * 16;

        const float* hj_row = nr + (b * N_ + j0 + col) * H_;
        floatx4 hjA0 = *(const floatx4*)(hj_row + quad * 8);
        floatx4 hjA1 = *(const floatx4*)(hj_row + quad * 8 + 4);
        floatx4 hjB0 = *(const floatx4*)(hj_row + 32 + quad * 8);
        floatx4 hjB1 = *(const floatx4*)(hj_row + 32 + quad * 8 + 4);

        short8 a0, a1, a2, a3;
#pragma unroll
        for (int t = 0; t < 4; t++) {
            a0[t]     = f2bf(fabsf(hiA0[t] - hjA0[t]));
            a0[t + 4] = f2bf(fabsf(hiA1[t] - hjA1[t]));
            a1[t]     = f2bf(fabsf(hiB0[t] - hjB0[t]));
            a1[t + 4] = f2bf(fabsf(hiB1[t] - hjB1[t]));
            a2[t]     = f2bf(hiA0[t] * hjA0[t]);
            a2[t + 4] = f2bf(hiA1[t] * hjA1[t]);
            a3[t]     = f2bf(hiB0[t] * hjB0[t]);
            a3[t + 4] = f2bf(hiB1[t] * hjB1[t]);
        }

        floatx4 acc[4];
#pragma unroll
        for (int nt = 0; nt < 4; nt++) acc[nt] = (floatx4){0.f, 0.f, 0.f, 0.f};
#pragma unroll
        for (int nt = 0; nt < 4; nt++) {
            acc[nt] = __builtin_amdgcn_mfma_f32_16x16x32_bf16(a0, bf[0][nt], acc[nt], 0, 0, 0);
            acc[nt] = __builtin_amdgcn_mfma_f32_16x16x32_bf16(a1, bf[1][nt], acc[nt], 0, 0, 0);
            acc[nt] = __builtin_amdgcn_mfma_f32_16x16x32_bf16(a2, bf[2][nt], acc[nt], 0, 0, 0);
            acc[nt] = __builtin_amdgcn_mfma_f32_16x16x32_bf16(a3, bf[3][nt], acc[nt], 0, 0, 0);
        }

        float ed[4];
#pragma unroll
        for (int r = 0; r < 4; r++) {
            int j = j0 + quad * 4 + r;
            float p = 0.f;
#pragma unroll
            for (int nt = 0; nt < 4; nt++) {
                float val = acc[nt][r] + pb3[nt] + Q[(b * N_ + j) * H_ + nt * 16 + col];
                p += fmaxf(val, 0.f) * w4v[nt];
            }
            p += __shfl_xor(p, 1);
            p += __shfl_xor(p, 2);
            p += __shfl_xor(p, 4);
            p += __shfl_xor(p, 8);
            float edge = fmaxf(p + b4s, 0.f);

            float d2 = 0.f;
#pragma unroll
            for (int c = 0; c < 8; c++) { float df = ci[c] - coords[j * 8 + c]; d2 += df * df; }
            float dist = (d2 > 0.f) ? sqrtf(d2) : 0.f;
            float pv = 1.f / (1.f + dist);
            float ad = (j == i) ? 1.0f : edge * pv;   // prior diag=0, SELF_LOOP_W=1
            ed[r] = ad;
            rsum += ad;   // same value on all 16 lanes of this quad-group
        }
        if (col == 0) {
            *(floatx4*)&adapt[(size_t)(b * N_ + i) * N_ + j0 + quad * 4] =
                (floatx4){ed[0], ed[1], ed[2], ed[3]};
        }
    }

    // per-quad partials are replicated across 16 lanes; sum the 4 quads only
    rsum += __shfl_xor(rsum, 16);
    rsum += __shfl_xor(rsum, 32);
    __shared__ float sRow[4];
    if (l == 0) sRow[w] = rsum;
    __syncthreads();
    if (tid == 0) degree[b * N_ + i] = sRow[0] + sRow[1] + sRow[2] + sRow[3];
}

// ---------------------------------------------------------------------------
// Kernel 4: symmetric normalization out = D^-1/2 A D^-1/2
// ---------------------------------------------------------------------------
__global__ void norm_kernel(const float* __restrict__ adapt, const float* __restrict__ deg,
                            float* __restrict__ out) {
    int idx = blockIdx.x * 256 + threadIdx.x;
    int b = idx >> 18;
    int r = (idx >> 9) & (N_ - 1);
    int c = idx & (N_ - 1);
    float dr = rsqrtf(fmaxf(deg[b * N_ + r], 1e-6f));
    float dc = rsqrtf(fmaxf(deg[b * N_ + c], 1e-6f));
    out[idx] = dr * adapt[idx] * dc;
}

extern "C" void kernel_launch(void* const* d_in, const int* in_sizes, int n_in,
                              void* d_out, int out_size, void* d_ws, size_t ws_size,
                              hipStream_t stream) {
    const float* x      = (const float*)d_in[0];
    const float* mask   = (const float*)d_in[1];
    const float* sc     = (const float*)d_in[2];
    const float* coords = (const float*)d_in[3];
    const float* W1 = (const float*)d_in[4];
    const float* b1 = (const float*)d_in[5];
    const float* W2 = (const float*)d_in[6];
    const float* b2 = (const float*)d_in[7];
    const float* W3 = (const float*)d_in[8];
    const float* b3 = (const float*)d_in[9];
    const float* W4 = (const float*)d_in[10];
    const float* b4 = (const float*)d_in[11];
    float* out = (float*)d_out;

    float* w = (float*)d_ws;
    float* dyn   = w;                      // B*N*4      = 4096
    float* nr    = w + 4096;               // B*N*64     = 65536
    float* P     = w + 69632;              // 65536
    float* Q     = w + 135168;             // 65536
    float* adapt = w + 200704;             // B*N*N      = 524288
    float* deg   = w + 724992;             // B*N        = 1024

    dyn_kernel<<<B_ * 32, 256, 0, stream>>>(x, mask, dyn);
    mlp_kernel<<<B_ * N_, 64, 0, stream>>>(dyn, sc, W1, b1, W2, b2, W3, nr, P, Q);
    pair_mfma_kernel<<<B_ * N_, 256, 0, stream>>>(nr, P, Q, W3, b3, W4, b4, coords, adapt, deg);
    norm_kernel<<<(B_ * N_ * N_) / 256, 256, 0, stream>>>(adapt, deg, out);
}

// Round 3
// 132.417 us; speedup vs baseline: 3.9996x; 1.0907x over previous
//
#include <hip/hip_runtime.h>
#include <hip/hip_bf16.h>
#include <math.h>

#define B_ 2
#define T_ 512
#define N_ 512
#define H_ 64

typedef __attribute__((ext_vector_type(8))) short short8;
typedef __attribute__((ext_vector_type(4))) float floatx4;

__device__ inline short f2bf(float f) {
    union { float f; unsigned u; } v; v.f = f;
    unsigned r = (v.u + 0x7fffu + ((v.u >> 16) & 1u)) >> 16;  // RNE
    return (short)r;
}

// ---------------------------------------------------------------------------
// Kernel 0: prep — prior adjacency table (blocks 0..1023) + W3cd bf16 pack in
// MFMA fragment order (blocks 1024..1055).
// W3p[((s*4+nt)*64 + l)*8 + t] = bf16(W3[(128+s*32+(l>>4)*8+t)*64 + nt*16+(l&15)])
// ---------------------------------------------------------------------------
__global__ void prep_kernel(const float* __restrict__ coords, const float* __restrict__ W3,
                            float* __restrict__ prior, short* __restrict__ W3p) {
    int idx = blockIdx.x * 256 + threadIdx.x;
    if (blockIdx.x < 1024) {
        int i = idx >> 9, j = idx & (N_ - 1);
        float d2 = 0.f;
#pragma unroll
        for (int c = 0; c < 8; c++) {
            float df = coords[i * 8 + c] - coords[j * 8 + c];
            d2 += df * df;
        }
        float dist = (d2 > 0.f) ? sqrtf(d2) : 0.f;
        prior[idx] = (i == j) ? 0.f : 1.f / (1.f + dist);
    } else {
        int k = idx - 1024 * 256;      // 0..8191
        int t = k & 7;
        int l = (k >> 3) & 63;
        int f = k >> 9;                // 0..15
        int s = f >> 2, nt = f & 3;
        int quad = l >> 4, col = l & 15;
        W3p[k] = f2bf(W3[(128 + s * 32 + quad * 8 + t) * H_ + nt * 16 + col]);
    }
}

// ---------------------------------------------------------------------------
// Kernel 1a: dyn partials. grid B*8*32 = 512 blocks; 256 thr = 64 n x 4 tt.
// Each block covers 16 t-steps for 64 nodes. part planes: sx,sxx,cnt,msum,bv,bt
// ---------------------------------------------------------------------------
__global__ void dyn_part_kernel(const float* __restrict__ x, const float* __restrict__ mask,
                                float* __restrict__ part) {
    int blk = blockIdx.x;
    int b  = blk >> 8;
    int nc = (blk >> 5) & 7;
    int tc = blk & 31;
    int tn = threadIdx.x & 63;
    int tt = threadIdx.x >> 6;
    int n  = nc * 64 + tn;

    float sx = 0.f, sxx = 0.f, cnt = 0.f, msum = 0.f, bv = 0.f, bt = -1.f;
#pragma unroll
    for (int it = 0; it < 4; it++) {
        int t = tc * 16 + it * 4 + tt;     // ascending per thread
        int off = (b * T_ + t) * N_ + n;
        float xv = x[off];
        float mv = mask[off];
        float obs = 1.f - mv;
        sx   += xv * obs;
        sxx  += xv * xv * obs;
        cnt  += obs;
        msum += mv;
        if (obs > 0.5f) { bt = (float)t; bv = xv; }
    }

    __shared__ float red[6][4][64];
    red[0][tt][tn] = sx;  red[1][tt][tn] = sxx; red[2][tt][tn] = cnt;
    red[3][tt][tn] = msum; red[4][tt][tn] = bv; red[5][tt][tn] = bt;
    __syncthreads();

    if (threadIdx.x < 64) {
        float Sx = 0.f, Sxx = 0.f, Cnt = 0.f, Ms = 0.f, Bv = 0.f, Bt = -1.f;
#pragma unroll
        for (int u = 0; u < 4; u++) {
            Sx  += red[0][u][tn];
            Sxx += red[1][u][tn];
            Cnt += red[2][u][tn];
            Ms  += red[3][u][tn];
            float btu = red[5][u][tn];
            if (btu > Bt) { Bt = btu; Bv = red[4][u][tn]; }
        }
        const int plane = B_ * 32 * N_;    // 32768
        int base = (b * 32 + tc) * N_ + n;
        part[0 * plane + base] = Sx;
        part[1 * plane + base] = Sxx;
        part[2 * plane + base] = Cnt;
        part[3 * plane + base] = Ms;
        part[4 * plane + base] = Bv;
        part[5 * plane + base] = Bt;
    }
}

// ---------------------------------------------------------------------------
// Kernel 1b: dyn final reduce. 4 blocks x 256 thr, one thread per (b,n).
// ---------------------------------------------------------------------------
__global__ void dyn_red_kernel(const float* __restrict__ part, const float* __restrict__ x,
                               float* __restrict__ dyn) {
    int u = blockIdx.x * 256 + threadIdx.x;    // 0..1023
    int b = u >> 9, n = u & (N_ - 1);
    const int plane = B_ * 32 * N_;
    float Sx = 0.f, Sxx = 0.f, Cnt = 0.f, Ms = 0.f, Bv = 0.f, Bt = -1.f;
    for (int tc = 0; tc < 32; tc++) {
        int base = (b * 32 + tc) * N_ + n;
        Sx  += part[0 * plane + base];
        Sxx += part[1 * plane + base];
        Cnt += part[2 * plane + base];
        Ms  += part[3 * plane + base];
        float bt = part[5 * plane + base];
        if (bt > Bt) { Bt = bt; Bv = part[4 * plane + base]; }
    }
    float count = fmaxf(Cnt, 1.f);
    float mean  = Sx / count;
    float var   = (Sxx - 2.f * mean * Sx + mean * mean * Cnt) / count;
    float stdv  = sqrtf(fmaxf(var, 0.f) + 1e-6f);
    float last  = (Bt >= 0.f) ? Bv : x[b * T_ * N_ + n];   // argmax of zeros -> t=0
    float mr    = Ms * (1.f / (float)T_);
    dyn[u * 4 + 0] = mean;
    dyn[u * 4 + 1] = stdv;
    dyn[u * 4 + 2] = last;
    dyn[u * 4 + 3] = mr;
}

// ---------------------------------------------------------------------------
// Kernel 2: per-node MLP (12 -> 64 -> 64) + P = r@W3[0:64], Qp = permuted
// r@W3[64:128] (Qp[(b*N+n)*64 + (o&15)*4 + (o>>4)] for float4 epilogue loads)
// ---------------------------------------------------------------------------
__global__ __launch_bounds__(64) void mlp_kernel(
        const float* __restrict__ dyn, const float* __restrict__ sc,
        const float* __restrict__ W1, const float* __restrict__ b1,
        const float* __restrict__ W2, const float* __restrict__ b2,
        const float* __restrict__ W3,
        float* __restrict__ nr, float* __restrict__ P, float* __restrict__ Qp) {
    int blk = blockIdx.x;
    int b = blk >> 9;
    int n = blk & (N_ - 1);
    int o = threadIdx.x;

    __shared__ float f[12];
    __shared__ float h[H_];
    __shared__ float r[H_];

    if (o < 4)        f[o] = dyn[(b * N_ + n) * 4 + o];
    else if (o < 12)  f[o] = sc[n * 8 + (o - 4)];
    __syncthreads();

    float a = b1[o];
#pragma unroll
    for (int k = 0; k < 12; k++) a += f[k] * W1[k * H_ + o];
    h[o] = fmaxf(a, 0.f);
    __syncthreads();

    float a2 = b2[o];
#pragma unroll 8
    for (int k = 0; k < H_; k++) a2 += h[k] * W2[k * H_ + o];
    float rv = fmaxf(a2, 0.f);
    r[o] = rv;
    nr[(b * N_ + n) * H_ + o] = rv;
    __syncthreads();

    float p = 0.f, q = 0.f;
#pragma unroll 8
    for (int k = 0; k < H_; k++) {
        float rk = r[k];
        p += rk * W3[k * H_ + o];
        q += rk * W3[(H_ + k) * H_ + o];
    }
    P[(b * N_ + n) * H_ + o] = p;
    Qp[(b * N_ + n) * H_ + (o & 15) * 4 + (o >> 4)] = q;
}

// ---------------------------------------------------------------------------
// Kernel 3 (MFMA): per (b,i), C[j,o] = [D|M](512x128) @ W3cd(128x64),
// fragments in registers; epilogue: +P+Qp+b3, relu, dot W4, relu, prior table.
// ---------------------------------------------------------------------------
__global__ __launch_bounds__(256) void pair_mfma_kernel(
        const float* __restrict__ nr, const float* __restrict__ P,
        const float* __restrict__ Qp, const short* __restrict__ W3p,
        const float* __restrict__ b3, const float* __restrict__ W4,
        const float* __restrict__ b4, const float* __restrict__ prior,
        float* __restrict__ adapt, float* __restrict__ degree) {
    int blk = blockIdx.x;
    int b = blk >> 9;
    int i = blk & (N_ - 1);
    int tid = threadIdx.x;
    int w = tid >> 6;
    int l = tid & 63;
    int col = l & 15;
    int quad = l >> 4;

    // B fragments: one 16B load each, pre-packed in fragment order
    short8 bf[4][4];
#pragma unroll
    for (int s = 0; s < 4; s++)
#pragma unroll
        for (int nt = 0; nt < 4; nt++)
            bf[s][nt] = *(const short8*)(W3p + (((s * 4 + nt) * 64 + l) << 3));

    const float* hi_row = nr + (b * N_ + i) * H_;
    floatx4 hiA0 = *(const floatx4*)(hi_row + quad * 8);
    floatx4 hiA1 = *(const floatx4*)(hi_row + quad * 8 + 4);
    floatx4 hiB0 = *(const floatx4*)(hi_row + 32 + quad * 8);
    floatx4 hiB1 = *(const floatx4*)(hi_row + 32 + quad * 8 + 4);

    float pb3[4], w4v[4];
#pragma unroll
    for (int nt = 0; nt < 4; nt++) {
        int o = nt * 16 + col;
        pb3[nt] = P[(b * N_ + i) * H_ + o] + b3[o];
        w4v[nt] = W4[o];
    }
    float b4s = b4[0];
    const float* prow = prior + i * N_;
    float rsum = 0.f;

    for (int mt = 0; mt < 8; mt++) {
        int j0 = w * 128 + mt * 16;

        const float* hj_row = nr + (b * N_ + j0 + col) * H_;
        floatx4 hjA0 = *(const floatx4*)(hj_row + quad * 8);
        floatx4 hjA1 = *(const floatx4*)(hj_row + quad * 8 + 4);
        floatx4 hjB0 = *(const floatx4*)(hj_row + 32 + quad * 8);
        floatx4 hjB1 = *(const floatx4*)(hj_row + 32 + quad * 8 + 4);

        union { short8 s; __hip_bfloat162 h[4]; } a0, a1, a2, a3;
#pragma unroll
        for (int t = 0; t < 2; t++) {
            a0.h[t]     = __float22bfloat162_rn(make_float2(fabsf(hiA0[2*t] - hjA0[2*t]),
                                                            fabsf(hiA0[2*t+1] - hjA0[2*t+1])));
            a0.h[t + 2] = __float22bfloat162_rn(make_float2(fabsf(hiA1[2*t] - hjA1[2*t]),
                                                            fabsf(hiA1[2*t+1] - hjA1[2*t+1])));
            a1.h[t]     = __float22bfloat162_rn(make_float2(fabsf(hiB0[2*t] - hjB0[2*t]),
                                                            fabsf(hiB0[2*t+1] - hjB0[2*t+1])));
            a1.h[t + 2] = __float22bfloat162_rn(make_float2(fabsf(hiB1[2*t] - hjB1[2*t]),
                                                            fabsf(hiB1[2*t+1] - hjB1[2*t+1])));
            a2.h[t]     = __float22bfloat162_rn(make_float2(hiA0[2*t] * hjA0[2*t],
                                                            hiA0[2*t+1] * hjA0[2*t+1]));
            a2.h[t + 2] = __float22bfloat162_rn(make_float2(hiA1[2*t] * hjA1[2*t],
                                                            hiA1[2*t+1] * hjA1[2*t+1]));
            a3.h[t]     = __float22bfloat162_rn(make_float2(hiB0[2*t] * hjB0[2*t],
                                                            hiB0[2*t+1] * hjB0[2*t+1]));
            a3.h[t + 2] = __float22bfloat162_rn(make_float2(hiB1[2*t] * hjB1[2*t],
                                                            hiB1[2*t+1] * hjB1[2*t+1]));
        }

        floatx4 acc[4];
#pragma unroll
        for (int nt = 0; nt < 4; nt++) acc[nt] = (floatx4){0.f, 0.f, 0.f, 0.f};
#pragma unroll
        for (int nt = 0; nt < 4; nt++) {
            acc[nt] = __builtin_amdgcn_mfma_f32_16x16x32_bf16(a0.s, bf[0][nt], acc[nt], 0, 0, 0);
            acc[nt] = __builtin_amdgcn_mfma_f32_16x16x32_bf16(a1.s, bf[1][nt], acc[nt], 0, 0, 0);
            acc[nt] = __builtin_amdgcn_mfma_f32_16x16x32_bf16(a2.s, bf[2][nt], acc[nt], 0, 0, 0);
            acc[nt] = __builtin_amdgcn_mfma_f32_16x16x32_bf16(a3.s, bf[3][nt], acc[nt], 0, 0, 0);
        }

        floatx4 pv = *(const floatx4*)(prow + j0 + quad * 4);  // broadcast over col
        float ed[4];
#pragma unroll
        for (int r = 0; r < 4; r++) {
            int j = j0 + quad * 4 + r;
            floatx4 qv = *(const floatx4*)(Qp + (b * N_ + j) * H_ + col * 4);
            float p = 0.f;
#pragma unroll
            for (int nt = 0; nt < 4; nt++)
                p += fmaxf(acc[nt][r] + pb3[nt] + qv[nt], 0.f) * w4v[nt];
            p += __shfl_xor(p, 1);
            p += __shfl_xor(p, 2);
            p += __shfl_xor(p, 4);
            p += __shfl_xor(p, 8);
            float edge = fmaxf(p + b4s, 0.f);
            float ad = (j == i) ? 1.0f : edge * pv[r];
            ed[r] = ad;
            rsum += ad;
        }
        if (col == 0) {
            *(floatx4*)&adapt[(size_t)(b * N_ + i) * N_ + j0 + quad * 4] =
                (floatx4){ed[0], ed[1], ed[2], ed[3]};
        }
    }

    rsum += __shfl_xor(rsum, 16);
    rsum += __shfl_xor(rsum, 32);
    __shared__ float sRow[4];
    if (l == 0) sRow[w] = rsum;
    __syncthreads();
    if (tid == 0) degree[b * N_ + i] = sRow[0] + sRow[1] + sRow[2] + sRow[3];
}

// ---------------------------------------------------------------------------
// Kernel 4: symmetric normalization out = D^-1/2 A D^-1/2 (float4)
// ---------------------------------------------------------------------------
__global__ void norm_kernel(const float* __restrict__ adapt, const float* __restrict__ deg,
                            float* __restrict__ out) {
    int idx = blockIdx.x * 256 + threadIdx.x;      // one float4 each
    int b = idx >> 16;
    int r = (idx >> 7) & (N_ - 1);
    int c4 = (idx & 127) << 2;
    float dr = rsqrtf(fmaxf(deg[b * N_ + r], 1e-6f));
    floatx4 a = *(const floatx4*)(adapt + ((size_t)idx << 2));
    floatx4 o;
#pragma unroll
    for (int k = 0; k < 4; k++)
        o[k] = dr * a[k] * rsqrtf(fmaxf(deg[b * N_ + c4 + k], 1e-6f));
    *(floatx4*)(out + ((size_t)idx << 2)) = o;
}

extern "C" void kernel_launch(void* const* d_in, const int* in_sizes, int n_in,
                              void* d_out, int out_size, void* d_ws, size_t ws_size,
                              hipStream_t stream) {
    const float* x      = (const float*)d_in[0];
    const float* mask   = (const float*)d_in[1];
    const float* sc     = (const float*)d_in[2];
    const float* coords = (const float*)d_in[3];
    const float* W1 = (const float*)d_in[4];
    const float* b1 = (const float*)d_in[5];
    const float* W2 = (const float*)d_in[6];
    const float* b2 = (const float*)d_in[7];
    const float* W3 = (const float*)d_in[8];
    const float* b3 = (const float*)d_in[9];
    const float* W4 = (const float*)d_in[10];
    const float* b4 = (const float*)d_in[11];
    float* out = (float*)d_out;

    float* w = (float*)d_ws;
    float* dyn   = w;                      // 4096
    float* nr    = w + 4096;               // 65536
    float* P     = w + 69632;              // 65536
    float* Qp    = w + 135168;             // 65536
    float* adapt = w + 200704;             // 524288 (part overlays this, dead before pair)
    float* deg   = w + 724992;             // 1024
    float* prior = w + 726016;             // 262144
    short* W3p   = (short*)(w + 988160);   // 8192 shorts
    float* part  = adapt;                  // 6*B*32*N = 196608 <= 524288

    prep_kernel<<<1056, 256, 0, stream>>>(coords, W3, prior, W3p);
    dyn_part_kernel<<<512, 256, 0, stream>>>(x, mask, part);
    dyn_red_kernel<<<4, 256, 0, stream>>>(part, x, dyn);
    mlp_kernel<<<B_ * N_, 64, 0, stream>>>(dyn, sc, W1, b1, W2, b2, W3, nr, P, Qp);
    pair_mfma_kernel<<<B_ * N_, 256, 0, stream>>>(nr, P, Qp, W3p, b3, W4, b4, prior, adapt, deg);
    norm_kernel<<<512, 256, 0, stream>>>(adapt, deg, out);
}

// Round 4
// 119.189 us; speedup vs baseline: 4.4435x; 1.1110x over previous
//
#include <hip/hip_runtime.h>
#include <hip/hip_bf16.h>
#include <math.h>

#define B_ 2
#define T_ 512
#define N_ 512
#define H_ 64

typedef __attribute__((ext_vector_type(8))) short short8;
typedef __attribute__((ext_vector_type(4))) float floatx4;

__device__ inline short f2bf(float f) {
    union { float f; unsigned u; } v; v.f = f;
    unsigned r = (v.u + 0x7fffu + ((v.u >> 16) & 1u)) >> 16;  // RNE
    return (short)r;
}

// ---------------------------------------------------------------------------
// Kernel 1 (fused prep): grid-partitioned independent work.
//   blocks 0..511     : dyn partials (B*8 n-chunks x 32 t-chunks)
//   blocks 512..1535  : prior adjacency table (512x512)
//   blocks 1536..1567 : W3[128:256] bf16 pack in MFMA fragment order
// ---------------------------------------------------------------------------
__global__ void prep_kernel(const float* __restrict__ x, const float* __restrict__ mask,
                            const float* __restrict__ coords, const float* __restrict__ W3,
                            float* __restrict__ part, float* __restrict__ prior,
                            short* __restrict__ W3p) {
    int blk = blockIdx.x;
    if (blk < 512) {
        // ---- dyn partials: 256 thr = 64 n x 4 tt, 16 t-steps per block ----
        int b  = blk >> 8;
        int nc = (blk >> 5) & 7;
        int tc = blk & 31;
        int tn = threadIdx.x & 63;
        int tt = threadIdx.x >> 6;
        int n  = nc * 64 + tn;

        float sx = 0.f, sxx = 0.f, cnt = 0.f, msum = 0.f, bv = 0.f, bt = -1.f;
#pragma unroll
        for (int it = 0; it < 4; it++) {
            int t = tc * 16 + it * 4 + tt;
            int off = (b * T_ + t) * N_ + n;
            float xv = x[off];
            float mv = mask[off];
            float obs = 1.f - mv;
            sx   += xv * obs;
            sxx  += xv * xv * obs;
            cnt  += obs;
            msum += mv;
            if (obs > 0.5f) { bt = (float)t; bv = xv; }
        }

        __shared__ float red[6][4][64];
        red[0][tt][tn] = sx;  red[1][tt][tn] = sxx; red[2][tt][tn] = cnt;
        red[3][tt][tn] = msum; red[4][tt][tn] = bv; red[5][tt][tn] = bt;
        __syncthreads();

        if (threadIdx.x < 64) {
            float Sx = 0.f, Sxx = 0.f, Cnt = 0.f, Ms = 0.f, Bv = 0.f, Bt = -1.f;
#pragma unroll
            for (int u = 0; u < 4; u++) {
                Sx  += red[0][u][tn];
                Sxx += red[1][u][tn];
                Cnt += red[2][u][tn];
                Ms  += red[3][u][tn];
                float btu = red[5][u][tn];
                if (btu > Bt) { Bt = btu; Bv = red[4][u][tn]; }
            }
            const int plane = B_ * 32 * N_;
            int base = (b * 32 + tc) * N_ + n;
            part[0 * plane + base] = Sx;
            part[1 * plane + base] = Sxx;
            part[2 * plane + base] = Cnt;
            part[3 * plane + base] = Ms;
            part[4 * plane + base] = Bv;
            part[5 * plane + base] = Bt;
        }
    } else if (blk < 1536) {
        // ---- prior table ----
        int idx = (blk - 512) * 256 + threadIdx.x;
        int i = idx >> 9, j = idx & (N_ - 1);
        float d2 = 0.f;
#pragma unroll
        for (int c = 0; c < 8; c++) {
            float df = coords[i * 8 + c] - coords[j * 8 + c];
            d2 += df * df;
        }
        float dist = (d2 > 0.f) ? sqrtf(d2) : 0.f;
        prior[idx] = (i == j) ? 0.f : 1.f / (1.f + dist);
    } else {
        // ---- W3cd pack: W3p[((s*4+nt)*64+l)*8+t] ----
        int k = (blk - 1536) * 256 + threadIdx.x;   // 0..8191
        int t = k & 7;
        int l = (k >> 3) & 63;
        int f = k >> 9;                // 0..15
        int s = f >> 2, nt = f & 3;
        int quad = l >> 4, col = l & 15;
        W3p[k] = f2bf(W3[(128 + s * 32 + quad * 8 + t) * H_ + nt * 16 + col]);
    }
}

// ---------------------------------------------------------------------------
// Kernel 2 (fused): dyn final reduce + node MLP (12->64->64) + P, permuted Q.
// One 64-thread block per (b,n).
// ---------------------------------------------------------------------------
__global__ __launch_bounds__(64) void node_kernel(
        const float* __restrict__ part, const float* __restrict__ x,
        const float* __restrict__ sc,
        const float* __restrict__ W1, const float* __restrict__ b1,
        const float* __restrict__ W2, const float* __restrict__ b2,
        const float* __restrict__ W3,
        float* __restrict__ nr, float* __restrict__ P, float* __restrict__ Qp) {
    int blk = blockIdx.x;
    int b = blk >> 9;
    int n = blk & (N_ - 1);
    int o = threadIdx.x;

    __shared__ float f[12];
    __shared__ float h[H_];
    __shared__ float r[H_];

    // ---- reduce 32 t-chunk partials (lanes 0..31, butterfly) ----
    {
        const int plane = B_ * 32 * N_;
        float Sx = 0.f, Sxx = 0.f, Cnt = 0.f, Ms = 0.f, Bv = 0.f, Bt = -1.f;
        if (o < 32) {
            int base = (b * 32 + o) * N_ + n;
            Sx  = part[0 * plane + base];
            Sxx = part[1 * plane + base];
            Cnt = part[2 * plane + base];
            Ms  = part[3 * plane + base];
            Bv  = part[4 * plane + base];
            Bt  = part[5 * plane + base];
        }
#pragma unroll
        for (int off = 1; off < 32; off <<= 1) {
            Sx  += __shfl_xor(Sx, off);
            Sxx += __shfl_xor(Sxx, off);
            Cnt += __shfl_xor(Cnt, off);
            Ms  += __shfl_xor(Ms, off);
            float obt = __shfl_xor(Bt, off);
            float obv = __shfl_xor(Bv, off);
            if (obt > Bt) { Bt = obt; Bv = obv; }
        }
        if (o == 0) {
            float count = fmaxf(Cnt, 1.f);
            float mean  = Sx / count;
            float var   = (Sxx - 2.f * mean * Sx + mean * mean * Cnt) / count;
            float stdv  = sqrtf(fmaxf(var, 0.f) + 1e-6f);
            float last  = (Bt >= 0.f) ? Bv : x[b * T_ * N_ + n];
            f[0] = mean; f[1] = stdv; f[2] = last; f[3] = Ms * (1.f / (float)T_);
        }
        if (o >= 4 && o < 12) f[o] = sc[n * 8 + (o - 4)];
    }
    __syncthreads();

    float a = b1[o];
#pragma unroll
    for (int k = 0; k < 12; k++) a += f[k] * W1[k * H_ + o];
    h[o] = fmaxf(a, 0.f);
    __syncthreads();

    float a2 = b2[o];
#pragma unroll 8
    for (int k = 0; k < H_; k++) a2 += h[k] * W2[k * H_ + o];
    float rv = fmaxf(a2, 0.f);
    r[o] = rv;
    nr[(b * N_ + n) * H_ + o] = rv;
    __syncthreads();

    float p = 0.f, q = 0.f;
#pragma unroll 8
    for (int k = 0; k < H_; k++) {
        float rk = r[k];
        p += rk * W3[k * H_ + o];
        q += rk * W3[(H_ + k) * H_ + o];
    }
    P[(b * N_ + n) * H_ + o] = p;
    Qp[(b * N_ + n) * H_ + (o & 15) * 4 + (o >> 4)] = q;
}

// ---------------------------------------------------------------------------
// Kernel 3 (MFMA): per (b,i), C[j,o] = [D|M](512x128) @ W3cd(128x64), with
// software-prefetched hj tiles; epilogue +P+Qp+b3, relu, dot W4, relu, prior.
// ---------------------------------------------------------------------------
__global__ __launch_bounds__(256) void pair_mfma_kernel(
        const float* __restrict__ nr, const float* __restrict__ P,
        const float* __restrict__ Qp, const short* __restrict__ W3p,
        const float* __restrict__ b3, const float* __restrict__ W4,
        const float* __restrict__ b4, const float* __restrict__ prior,
        float* __restrict__ adapt, float* __restrict__ degree) {
    int blk = blockIdx.x;
    int b = blk >> 9;
    int i = blk & (N_ - 1);
    int tid = threadIdx.x;
    int w = tid >> 6;
    int l = tid & 63;
    int col = l & 15;
    int quad = l >> 4;

    // B fragments: one 16B load each, pre-packed in fragment order
    short8 bf[4][4];
#pragma unroll
    for (int s = 0; s < 4; s++)
#pragma unroll
        for (int nt = 0; nt < 4; nt++)
            bf[s][nt] = *(const short8*)(W3p + (((s * 4 + nt) * 64 + l) << 3));

    const float* hi_row = nr + (b * N_ + i) * H_;
    floatx4 hiA0 = *(const floatx4*)(hi_row + quad * 8);
    floatx4 hiA1 = *(const floatx4*)(hi_row + quad * 8 + 4);
    floatx4 hiB0 = *(const floatx4*)(hi_row + 32 + quad * 8);
    floatx4 hiB1 = *(const floatx4*)(hi_row + 32 + quad * 8 + 4);

    float pb3[4], w4v[4];
#pragma unroll
    for (int nt = 0; nt < 4; nt++) {
        int o = nt * 16 + col;
        pb3[nt] = P[(b * N_ + i) * H_ + o] + b3[o];
        w4v[nt] = W4[o];
    }
    float b4s = b4[0];
    const float* prow = prior + i * N_;
    const float* nrb = nr + (b * N_) * H_;
    float rsum = 0.f;

    // prefetch tile 0
    floatx4 hA0, hA1, hB0, hB1;
    {
        const float* p0 = nrb + (w * 128 + col) * H_;
        hA0 = *(const floatx4*)(p0 + quad * 8);
        hA1 = *(const floatx4*)(p0 + quad * 8 + 4);
        hB0 = *(const floatx4*)(p0 + 32 + quad * 8);
        hB1 = *(const floatx4*)(p0 + 32 + quad * 8 + 4);
    }

#pragma unroll
    for (int mt = 0; mt < 8; mt++) {
        int j0 = w * 128 + mt * 16;

        // prefetch next hj tile
        floatx4 nA0, nA1, nB0, nB1;
        if (mt < 7) {
            const float* pn = nrb + (j0 + 16 + col) * H_;
            nA0 = *(const floatx4*)(pn + quad * 8);
            nA1 = *(const floatx4*)(pn + quad * 8 + 4);
            nB0 = *(const floatx4*)(pn + 32 + quad * 8);
            nB1 = *(const floatx4*)(pn + 32 + quad * 8 + 4);
        }

        // epilogue operands issued early (hide L2 latency under cvt+MFMA)
        floatx4 pv = *(const floatx4*)(prow + j0 + quad * 4);
        floatx4 qv[4];
#pragma unroll
        for (int r = 0; r < 4; r++)
            qv[r] = *(const floatx4*)(Qp + (b * N_ + j0 + quad * 4 + r) * H_ + col * 4);

        union { short8 s; __hip_bfloat162 h[4]; } a0, a1, a2, a3;
#pragma unroll
        for (int t = 0; t < 2; t++) {
            a0.h[t]     = __float22bfloat162_rn(make_float2(fabsf(hiA0[2*t] - hA0[2*t]),
                                                            fabsf(hiA0[2*t+1] - hA0[2*t+1])));
            a0.h[t + 2] = __float22bfloat162_rn(make_float2(fabsf(hiA1[2*t] - hA1[2*t]),
                                                            fabsf(hiA1[2*t+1] - hA1[2*t+1])));
            a1.h[t]     = __float22bfloat162_rn(make_float2(fabsf(hiB0[2*t] - hB0[2*t]),
                                                            fabsf(hiB0[2*t+1] - hB0[2*t+1])));
            a1.h[t + 2] = __float22bfloat162_rn(make_float2(fabsf(hiB1[2*t] - hB1[2*t]),
                                                            fabsf(hiB1[2*t+1] - hB1[2*t+1])));
            a2.h[t]     = __float22bfloat162_rn(make_float2(hiA0[2*t] * hA0[2*t],
                                                            hiA0[2*t+1] * hA0[2*t+1]));
            a2.h[t + 2] = __float22bfloat162_rn(make_float2(hiA1[2*t] * hA1[2*t],
                                                            hiA1[2*t+1] * hA1[2*t+1]));
            a3.h[t]     = __float22bfloat162_rn(make_float2(hiB0[2*t] * hB0[2*t],
                                                            hiB0[2*t+1] * hB0[2*t+1]));
            a3.h[t + 2] = __float22bfloat162_rn(make_float2(hiB1[2*t] * hB1[2*t],
                                                            hiB1[2*t+1] * hB1[2*t+1]));
        }

        floatx4 acc[4];
#pragma unroll
        for (int nt = 0; nt < 4; nt++) acc[nt] = (floatx4){0.f, 0.f, 0.f, 0.f};
#pragma unroll
        for (int nt = 0; nt < 4; nt++) {
            acc[nt] = __builtin_amdgcn_mfma_f32_16x16x32_bf16(a0.s, bf[0][nt], acc[nt], 0, 0, 0);
            acc[nt] = __builtin_amdgcn_mfma_f32_16x16x32_bf16(a1.s, bf[1][nt], acc[nt], 0, 0, 0);
            acc[nt] = __builtin_amdgcn_mfma_f32_16x16x32_bf16(a2.s, bf[2][nt], acc[nt], 0, 0, 0);
            acc[nt] = __builtin_amdgcn_mfma_f32_16x16x32_bf16(a3.s, bf[3][nt], acc[nt], 0, 0, 0);
        }

        float ed[4];
#pragma unroll
        for (int r = 0; r < 4; r++) {
            int j = j0 + quad * 4 + r;
            float p = 0.f;
#pragma unroll
            for (int nt = 0; nt < 4; nt++)
                p += fmaxf(acc[nt][r] + pb3[nt] + qv[r][nt], 0.f) * w4v[nt];
            p += __shfl_xor(p, 1);
            p += __shfl_xor(p, 2);
            p += __shfl_xor(p, 4);
            p += __shfl_xor(p, 8);
            float edge = fmaxf(p + b4s, 0.f);
            float ad = (j == i) ? 1.0f : edge * pv[r];
            ed[r] = ad;
            rsum += ad;
        }
        if (col == 0) {
            *(floatx4*)&adapt[(size_t)(b * N_ + i) * N_ + j0 + quad * 4] =
                (floatx4){ed[0], ed[1], ed[2], ed[3]};
        }

        if (mt < 7) { hA0 = nA0; hA1 = nA1; hB0 = nB0; hB1 = nB1; }
    }

    rsum += __shfl_xor(rsum, 16);
    rsum += __shfl_xor(rsum, 32);
    __shared__ float sRow[4];
    if (l == 0) sRow[w] = rsum;
    __syncthreads();
    if (tid == 0) degree[b * N_ + i] = sRow[0] + sRow[1] + sRow[2] + sRow[3];
}

// ---------------------------------------------------------------------------
// Kernel 4: symmetric normalization out = D^-1/2 A D^-1/2 (float4)
// ---------------------------------------------------------------------------
__global__ void norm_kernel(const float* __restrict__ adapt, const float* __restrict__ deg,
                            float* __restrict__ out) {
    int idx = blockIdx.x * 256 + threadIdx.x;      // one float4 each
    int b = idx >> 16;
    int r = (idx >> 7) & (N_ - 1);
    int c4 = (idx & 127) << 2;
    float dr = rsqrtf(fmaxf(deg[b * N_ + r], 1e-6f));
    floatx4 a = *(const floatx4*)(adapt + ((size_t)idx << 2));
    floatx4 o;
#pragma unroll
    for (int k = 0; k < 4; k++)
        o[k] = dr * a[k] * rsqrtf(fmaxf(deg[b * N_ + c4 + k], 1e-6f));
    *(floatx4*)(out + ((size_t)idx << 2)) = o;
}

extern "C" void kernel_launch(void* const* d_in, const int* in_sizes, int n_in,
                              void* d_out, int out_size, void* d_ws, size_t ws_size,
                              hipStream_t stream) {
    const float* x      = (const float*)d_in[0];
    const float* mask   = (const float*)d_in[1];
    const float* sc     = (const float*)d_in[2];
    const float* coords = (const float*)d_in[3];
    const float* W1 = (const float*)d_in[4];
    const float* b1 = (const float*)d_in[5];
    const float* W2 = (const float*)d_in[6];
    const float* b2 = (const float*)d_in[7];
    const float* W3 = (const float*)d_in[8];
    const float* b3 = (const float*)d_in[9];
    const float* W4 = (const float*)d_in[10];
    const float* b4 = (const float*)d_in[11];
    float* out = (float*)d_out;

    float* wsp = (float*)d_ws;
    float* nr    = wsp;                      // 65536
    float* P     = wsp + 65536;              // 65536
    float* Qp    = wsp + 131072;             // 65536
    float* prior = wsp + 196608;             // 262144
    short* W3p   = (short*)(wsp + 458752);   // 8192 shorts (4096 floats)
    float* deg   = wsp + 462848;             // 1024
    float* adapt = wsp + 463872;             // 524288; partials overlay (196608 floats)
    float* part  = adapt;

    prep_kernel<<<1568, 256, 0, stream>>>(x, mask, coords, W3, part, prior, W3p);
    node_kernel<<<B_ * N_, 64, 0, stream>>>(part, x, sc, W1, b1, W2, b2, W3, nr, P, Qp);
    pair_mfma_kernel<<<B_ * N_, 256, 0, stream>>>(nr, P, Qp, W3p, b3, W4, b4, prior, adapt, deg);
    norm_kernel<<<512, 256, 0, stream>>>(adapt, deg, out);
}